// Round 4
// baseline (599.281 us; speedup 1.0000x reference)
//
#include <hip/hip_runtime.h>

// Simple GNN: h = X@W_in+b; 4x { agg = segmean(w*h[src], dst); h += lrelu(agg@W_l+b_l) }
// out = (h@W_out+b_out, h)
// Round 4: fused gather+GEMM layer (1 node per half-wave, ds_read_b64 broadcast GEMM),
//          h ping-pong between d_out region and workspace.

#define N_NODES 50000
#define N_EDGES 625000
#define IN_F 64
#define INT_F 128
#define OUT_F 32
#define DEPTH 4
#define NEG_SLOPE 0.01f

#define SCAN_BLOCKS 196  // 196*256 = 50176 >= N_NODES

// ---- in-degree (int) ----
__global__ void deg_kernel(const int2* __restrict__ ei, int* __restrict__ deg) {
    int i = blockIdx.x * blockDim.x + threadIdx.x;
    if (i < N_EDGES) atomicAdd(&deg[ei[i].y], 1);
}

// ---- scan stage 1: per-block sum of 256 degrees ----
__global__ void scan1_kernel(const int* __restrict__ deg, int* __restrict__ partial) {
    int node = blockIdx.x * 256 + threadIdx.x;
    int v = (node < N_NODES) ? deg[node] : 0;
    __shared__ int sd[256];
    sd[threadIdx.x] = v;
    __syncthreads();
    for (int off = 128; off > 0; off >>= 1) {
        if (threadIdx.x < off) sd[threadIdx.x] += sd[threadIdx.x + off];
        __syncthreads();
    }
    if (threadIdx.x == 0) partial[blockIdx.x] = sd[0];
}

// ---- scan stage 2: single block scans the 196 partials -> exclusive block bases ----
__global__ void scan2_kernel(const int* __restrict__ partial, int* __restrict__ base,
                             int* __restrict__ row_ptr) {
    __shared__ int ps[256];
    int t = threadIdx.x;
    int v = (t < SCAN_BLOCKS) ? partial[t] : 0;
    ps[t] = v;
    __syncthreads();
    for (int off = 1; off < 256; off <<= 1) {
        int add = (t >= off) ? ps[t - off] : 0;
        __syncthreads();
        ps[t] += add;
        __syncthreads();
    }
    if (t < SCAN_BLOCKS) base[t] = ps[t] - v;  // exclusive
    if (t == SCAN_BLOCKS - 1) row_ptr[N_NODES] = ps[t];
}

// ---- scan stage 3: local inclusive scan + base -> row_ptr, cursor ----
__global__ void scan3_kernel(const int* __restrict__ deg, const int* __restrict__ base,
                             int* __restrict__ row_ptr, int* __restrict__ cursor) {
    int node = blockIdx.x * 256 + threadIdx.x;
    int t = threadIdx.x;
    int d = (node < N_NODES) ? deg[node] : 0;
    __shared__ int ps[256];
    ps[t] = d;
    __syncthreads();
    for (int off = 1; off < 256; off <<= 1) {
        int add = (t >= off) ? ps[t - off] : 0;
        __syncthreads();
        ps[t] += add;
        __syncthreads();
    }
    if (node < N_NODES) {
        int excl = base[blockIdx.x] + ps[t] - d;
        row_ptr[node] = excl;
        cursor[node] = excl;
    }
}

// ---- scatter edges into CSR slots ----
__global__ void build_csr_kernel(const int2* __restrict__ ei, const float* __restrict__ ew,
                                 int* __restrict__ cursor, int* __restrict__ csr_src,
                                 float* __restrict__ csr_w) {
    int e = blockIdx.x * blockDim.x + threadIdx.x;
    if (e >= N_EDGES) return;
    int2 sd = ei[e];
    int pos = atomicAdd(&cursor[sd.y], 1);
    csr_src[pos] = sd.x;
    csr_w[pos] = ew[e];
}

// ---- h = X @ W_in + b_in  (16 nodes per 256-thread block) ----
__global__ void gemm_in_kernel(const float* __restrict__ X, const float* __restrict__ W,
                               const float* __restrict__ b, float* __restrict__ h) {
    __shared__ float xs[16][IN_F];
    const int base = blockIdx.x * 16;
    const int t = threadIdx.x;
    ((float4*)xs)[t] = ((const float4*)(X + (size_t)base * IN_F))[t];
    __syncthreads();
    const int f = t & (INT_F - 1);
    const int rg = t >> 7;
    float acc[8];
    const float bv = b[f];
#pragma unroll
    for (int j = 0; j < 8; ++j) acc[j] = bv;
    for (int k = 0; k < IN_F; ++k) {
        float w = W[k * INT_F + f];
#pragma unroll
        for (int j = 0; j < 8; ++j) acc[j] += xs[rg * 8 + j][k] * w;
    }
#pragma unroll
    for (int j = 0; j < 8; ++j) h[(size_t)(base + rg * 8 + j) * INT_F + f] = acc[j];
}

// ---- fused layer: per node (half-wave): agg = segmean; z = agg@W+b; h_out = h_in + lrelu(z) ----
// 256 threads = 8 half-waves = 8 nodes per block. N_NODES = 50000 = 6250 * 8 exactly.
__global__ void fused_layer_kernel(const int* __restrict__ row_ptr, const int* __restrict__ csr_src,
                                   const float* __restrict__ csr_w, const float4* __restrict__ h_in4,
                                   const float4* __restrict__ W4, const float4* __restrict__ b4,
                                   float4* __restrict__ h_out4) {
    __shared__ float as_[8][INT_F];  // per-half-wave private row
    const int nl = threadIdx.x >> 5;   // local node 0..7
    const int l = threadIdx.x & 31;    // lane-in-half 0..31 -> features 4l..4l+3
    const int node = blockIdx.x * 8 + nl;

    const int s = row_ptr[node], e = row_ptr[node + 1];

    // ---- phase 1: gather agg (float4 per lane) ----
    float4 acc = {0.f, 0.f, 0.f, 0.f};
    int i = s;
    for (; i + 1 < e; i += 2) {
        int src0 = csr_src[i], src1 = csr_src[i + 1];
        float w0 = csr_w[i], w1 = csr_w[i + 1];
        float4 a = h_in4[(size_t)src0 * 32 + l];
        float4 c = h_in4[(size_t)src1 * 32 + l];
        acc.x += w0 * a.x + w1 * c.x;
        acc.y += w0 * a.y + w1 * c.y;
        acc.z += w0 * a.z + w1 * c.z;
        acc.w += w0 * a.w + w1 * c.w;
    }
    if (i < e) {
        int src = csr_src[i];
        float w = csr_w[i];
        float4 a = h_in4[(size_t)src * 32 + l];
        acc.x += w * a.x; acc.y += w * a.y; acc.z += w * a.z; acc.w += w * a.w;
    }
    float inv = 1.0f / fmaxf((float)(e - s), 1.0f);
    acc.x *= inv; acc.y *= inv; acc.z *= inv; acc.w *= inv;

    // stage own row to LDS (producer == consumer half-wave; no barrier needed)
    ((float4*)as_[nl])[l] = acc;

    // ---- phase 2: z = agg @ W + b via ds_read_b64 broadcast ----
    float4 z = b4[l];
    const float2* arow = (const float2*)as_[nl];
#pragma unroll 8
    for (int m = 0; m < INT_F / 2; ++m) {
        float2 av = arow[m];  // broadcast across half-wave
        float4 w0 = W4[(size_t)(2 * m) * 32 + l];
        float4 w1 = W4[(size_t)(2 * m + 1) * 32 + l];
        z.x += av.x * w0.x + av.y * w1.x;
        z.y += av.x * w0.y + av.y * w1.y;
        z.z += av.x * w0.z + av.y * w1.z;
        z.w += av.x * w0.w + av.y * w1.w;
    }

    // ---- phase 3: residual + leaky relu ----
    float4 hv = h_in4[(size_t)node * 32 + l];
    hv.x += (z.x >= 0.f) ? z.x : NEG_SLOPE * z.x;
    hv.y += (z.y >= 0.f) ? z.y : NEG_SLOPE * z.y;
    hv.z += (z.z >= 0.f) ? z.z : NEG_SLOPE * z.z;
    hv.w += (z.w >= 0.f) ? z.w : NEG_SLOPE * z.w;
    h_out4[(size_t)node * 32 + l] = hv;
}

// ---- out = h @ W_out + b_out  (8 nodes per 256-thread block) ----
__global__ void gemm_out_kernel(const float* __restrict__ h, const float* __restrict__ W,
                                const float* __restrict__ b, float* __restrict__ out) {
    __shared__ float hr[8][INT_F];
    int base = blockIdx.x * 8;
    for (int t = threadIdx.x; t < 8 * INT_F; t += 256) {
        int n = t / INT_F, k = t % INT_F;
        int gn = base + n;
        hr[n][k] = (gn < N_NODES) ? h[(size_t)gn * INT_F + k] : 0.0f;
    }
    __syncthreads();
    int nl = threadIdx.x / OUT_F;
    int f = threadIdx.x % OUT_F;
    int node = base + nl;
    if (node >= N_NODES) return;
    float acc = b[f];
#pragma unroll 8
    for (int k = 0; k < INT_F; ++k) acc += hr[nl][k] * W[k * OUT_F + f];
    out[(size_t)node * OUT_F + f] = acc;
}

extern "C" void kernel_launch(void* const* d_in, const int* in_sizes, int n_in,
                              void* d_out, int out_size, void* d_ws, size_t ws_size,
                              hipStream_t stream) {
    const float* X        = (const float*)d_in[0];
    const int2*  ei       = (const int2*)d_in[1];
    const float* ew       = (const float*)d_in[2];
    const float* W_in     = (const float*)d_in[3];
    const float* b_in     = (const float*)d_in[4];
    const float* W_layers = (const float*)d_in[5];
    const float* b_layers = (const float*)d_in[6];
    const float* W_out    = (const float*)d_in[7];
    const float* b_out    = (const float*)d_in[8];

    float* out1 = (float*)d_out;                   // (N_NODES, OUT_F)
    float* hA   = out1 + (size_t)N_NODES * OUT_F;  // (N_NODES, INT_F) -- second output doubles as h

    // workspace layout
    char* ws = (char*)d_ws;
    float* hB      = (float*)ws;  ws += (size_t)N_NODES * INT_F * 4;  // 25.6 MB ping-pong buffer
    float* csr_w   = (float*)ws;  ws += (size_t)N_EDGES * 4;          // 2.5 MB
    int*   csr_src = (int*)ws;    ws += (size_t)N_EDGES * 4;          // 2.5 MB
    int*   row_ptr = (int*)ws;    ws += (size_t)(N_NODES + 1) * 4;
    int*   cursor  = (int*)ws;    ws += (size_t)N_NODES * 4;
    int*   deg     = (int*)ws;    ws += (size_t)N_NODES * 4;
    int*   partial = (int*)ws;    ws += (size_t)SCAN_BLOCKS * 4;
    int*   bbase   = (int*)ws;    ws += (size_t)SCAN_BLOCKS * 4;

    // ---- build CSR (once per call) ----
    hipMemsetAsync(deg, 0, (size_t)N_NODES * 4, stream);
    deg_kernel<<<(N_EDGES + 255) / 256, 256, 0, stream>>>(ei, deg);
    scan1_kernel<<<SCAN_BLOCKS, 256, 0, stream>>>(deg, partial);
    scan2_kernel<<<1, 256, 0, stream>>>(partial, bbase, row_ptr);
    scan3_kernel<<<SCAN_BLOCKS, 256, 0, stream>>>(deg, bbase, row_ptr, cursor);
    build_csr_kernel<<<(N_EDGES + 255) / 256, 256, 0, stream>>>(ei, ew, cursor, csr_src, csr_w);

    // ---- input projection (into hA) ----
    gemm_in_kernel<<<N_NODES / 16, 256, 0, stream>>>(X, W_in, b_in, hA);

    // ---- layers: ping-pong hA <-> hB (DEPTH=4 even -> final lands in hA = d_out region) ----
    float* hin = hA;
    float* hout = hB;
    for (int i = 0; i < DEPTH; ++i) {
        fused_layer_kernel<<<N_NODES / 8, 256, 0, stream>>>(
            row_ptr, csr_src, csr_w, (const float4*)hin,
            (const float4*)(W_layers + (size_t)i * INT_F * INT_F),
            (const float4*)(b_layers + (size_t)i * INT_F), (float4*)hout);
        float* tmp = hin; hin = hout; hout = tmp;
    }

    // ---- output projection (hin == hA here) ----
    gemm_out_kernel<<<(N_NODES + 7) / 8, 256, 0, stream>>>(hin, W_out, b_out, out1);
}

// Round 5
// 438.925 us; speedup vs baseline: 1.3653x; 1.3653x over previous
//
#include <hip/hip_runtime.h>
#include <hip/hip_fp16.h>

// Simple GNN: h = X@W_in+b; 4x { agg = segmean(w*h[src], dst); h += lrelu(agg@W_l+b_l) }
// out = (h@W_out+b_out, h)
// Round 5: split structure (revert round-4 fusion); fp16 mirror of h for the gather
//          (halves L3-bound row traffic); fp16 agg; layer GEMM k-unrolled x4 with
//          ds_read_b128 broadcasts (16x fewer LDS ops).

#define N_NODES 50000
#define N_EDGES 625000
#define IN_F 64
#define INT_F 128
#define OUT_F 32
#define DEPTH 4
#define NEG_SLOPE 0.01f

#define SCAN_BLOCKS 196  // 196*256 = 50176 >= N_NODES

// ---- in-degree (int) ----
__global__ void deg_kernel(const int2* __restrict__ ei, int* __restrict__ deg) {
    int i = blockIdx.x * blockDim.x + threadIdx.x;
    if (i < N_EDGES) atomicAdd(&deg[ei[i].y], 1);
}

// ---- scan stage 1: per-block sum of 256 degrees ----
__global__ void scan1_kernel(const int* __restrict__ deg, int* __restrict__ partial) {
    int node = blockIdx.x * 256 + threadIdx.x;
    int v = (node < N_NODES) ? deg[node] : 0;
    __shared__ int sd[256];
    sd[threadIdx.x] = v;
    __syncthreads();
    for (int off = 128; off > 0; off >>= 1) {
        if (threadIdx.x < off) sd[threadIdx.x] += sd[threadIdx.x + off];
        __syncthreads();
    }
    if (threadIdx.x == 0) partial[blockIdx.x] = sd[0];
}

// ---- scan stage 2: single block scans the 196 partials -> exclusive block bases ----
__global__ void scan2_kernel(const int* __restrict__ partial, int* __restrict__ base,
                             int* __restrict__ row_ptr) {
    __shared__ int ps[256];
    int t = threadIdx.x;
    int v = (t < SCAN_BLOCKS) ? partial[t] : 0;
    ps[t] = v;
    __syncthreads();
    for (int off = 1; off < 256; off <<= 1) {
        int add = (t >= off) ? ps[t - off] : 0;
        __syncthreads();
        ps[t] += add;
        __syncthreads();
    }
    if (t < SCAN_BLOCKS) base[t] = ps[t] - v;  // exclusive
    if (t == SCAN_BLOCKS - 1) row_ptr[N_NODES] = ps[t];
}

// ---- scan stage 3: local inclusive scan + base -> row_ptr, cursor ----
__global__ void scan3_kernel(const int* __restrict__ deg, const int* __restrict__ base,
                             int* __restrict__ row_ptr, int* __restrict__ cursor) {
    int node = blockIdx.x * 256 + threadIdx.x;
    int t = threadIdx.x;
    int d = (node < N_NODES) ? deg[node] : 0;
    __shared__ int ps[256];
    ps[t] = d;
    __syncthreads();
    for (int off = 1; off < 256; off <<= 1) {
        int add = (t >= off) ? ps[t - off] : 0;
        __syncthreads();
        ps[t] += add;
        __syncthreads();
    }
    if (node < N_NODES) {
        int excl = base[blockIdx.x] + ps[t] - d;
        row_ptr[node] = excl;
        cursor[node] = excl;
    }
}

// ---- scatter edges into CSR slots ----
__global__ void build_csr_kernel(const int2* __restrict__ ei, const float* __restrict__ ew,
                                 int* __restrict__ cursor, int* __restrict__ csr_src,
                                 float* __restrict__ csr_w) {
    int e = blockIdx.x * blockDim.x + threadIdx.x;
    if (e >= N_EDGES) return;
    int2 sd = ei[e];
    int pos = atomicAdd(&cursor[sd.y], 1);
    csr_src[pos] = sd.x;
    csr_w[pos] = ew[e];
}

// ---- h = X @ W_in + b_in  (16 nodes per 256-thread block); also writes fp16 mirror ----
__global__ void gemm_in_kernel(const float* __restrict__ X, const float* __restrict__ W,
                               const float* __restrict__ b, float* __restrict__ h,
                               __half* __restrict__ h16) {
    __shared__ float xs[16][IN_F];
    const int base = blockIdx.x * 16;
    const int t = threadIdx.x;
    ((float4*)xs)[t] = ((const float4*)(X + (size_t)base * IN_F))[t];
    __syncthreads();
    const int f = t & (INT_F - 1);
    const int rg = t >> 7;
    float acc[8];
    const float bv = b[f];
#pragma unroll
    for (int j = 0; j < 8; ++j) acc[j] = bv;
#pragma unroll 4
    for (int k = 0; k < IN_F; ++k) {
        float w = W[k * INT_F + f];
#pragma unroll
        for (int j = 0; j < 8; ++j) acc[j] += xs[rg * 8 + j][k] * w;
    }
#pragma unroll
    for (int j = 0; j < 8; ++j) {
        size_t idx = (size_t)(base + rg * 8 + j) * INT_F + f;
        h[idx] = acc[j];
        h16[idx] = __float2half(acc[j]);
    }
}

// ---- agg16[n] = (1/deg) * sum w_e * h16[src_e]  (half-wave per node, 4 halves/lane) ----
__global__ void gather_kernel(const int* __restrict__ row_ptr, const int* __restrict__ csr_src,
                              const float* __restrict__ csr_w, const uint2* __restrict__ h16v,
                              uint2* __restrict__ agg16v) {
    int gid = blockIdx.x * blockDim.x + threadIdx.x;
    int node = gid >> 5;  // half-wave per node
    int l = threadIdx.x & 31;
    if (node >= N_NODES) return;
    int s = row_ptr[node], e = row_ptr[node + 1];
    float4 acc = {0.f, 0.f, 0.f, 0.f};
    int i = s;
    for (; i + 1 < e; i += 2) {
        int s0 = csr_src[i], s1 = csr_src[i + 1];
        float w0 = csr_w[i], w1 = csr_w[i + 1];
        uint2 a = h16v[(size_t)s0 * 32 + l];  // 256B per row per half-wave
        uint2 c = h16v[(size_t)s1 * 32 + l];
        float2 a0 = __half22float2(*(const __half2*)&a.x);
        float2 a1 = __half22float2(*(const __half2*)&a.y);
        float2 c0 = __half22float2(*(const __half2*)&c.x);
        float2 c1 = __half22float2(*(const __half2*)&c.y);
        acc.x += w0 * a0.x + w1 * c0.x;
        acc.y += w0 * a0.y + w1 * c0.y;
        acc.z += w0 * a1.x + w1 * c1.x;
        acc.w += w0 * a1.y + w1 * c1.y;
    }
    if (i < e) {
        int s0 = csr_src[i];
        float w0 = csr_w[i];
        uint2 a = h16v[(size_t)s0 * 32 + l];
        float2 a0 = __half22float2(*(const __half2*)&a.x);
        float2 a1 = __half22float2(*(const __half2*)&a.y);
        acc.x += w0 * a0.x;
        acc.y += w0 * a0.y;
        acc.z += w0 * a1.x;
        acc.w += w0 * a1.y;
    }
    float inv = 1.0f / fmaxf((float)(e - s), 1.0f);
    __half2 o0 = __floats2half2_rn(acc.x * inv, acc.y * inv);
    __half2 o1 = __floats2half2_rn(acc.z * inv, acc.w * inv);
    uint2 o;
    o.x = *(const unsigned int*)&o0;
    o.y = *(const unsigned int*)&o1;
    agg16v[(size_t)node * 32 + l] = o;
}

// ---- z = agg @ W + b ; h += lrelu(z); h16 = fp16(h)  (32 nodes per 256-thread block) ----
__global__ void layer_gemm_kernel(const uint4* __restrict__ agg16q, const float* __restrict__ W,
                                  const float* __restrict__ b, float* __restrict__ h,
                                  __half* __restrict__ h16) {
    __shared__ float as[32][INT_F];  // 16KB
    const int base = blockIdx.x * 32;
    const int t = threadIdx.x;
    // stage 32 rows x 128 halves = 512 uint4; 2 per thread; convert to fp32 in LDS
#pragma unroll
    for (int it = 0; it < 2; ++it) {
        int idx = t + it * 256;
        uint4 v = agg16q[(size_t)base * 16 + idx];  // 16 uint4 per row
        int row = idx >> 4;
        int col = (idx & 15) << 3;
        float* dst = &as[row][col];
        float2 f0 = __half22float2(*(const __half2*)&v.x);
        float2 f1 = __half22float2(*(const __half2*)&v.y);
        float2 f2 = __half22float2(*(const __half2*)&v.z);
        float2 f3 = __half22float2(*(const __half2*)&v.w);
        dst[0] = f0.x; dst[1] = f0.y; dst[2] = f1.x; dst[3] = f1.y;
        dst[4] = f2.x; dst[5] = f2.y; dst[6] = f3.x; dst[7] = f3.y;
    }
    __syncthreads();
    const int f = t & (INT_F - 1);
    const int rg = t >> 7;  // 0..1 -> rows rg*16..rg*16+15
    float acc[16];
    const float bv = b[f];
#pragma unroll
    for (int j = 0; j < 16; ++j) acc[j] = bv;
    for (int kg = 0; kg < INT_F / 4; ++kg) {
        float w0 = W[(4 * kg + 0) * INT_F + f];
        float w1 = W[(4 * kg + 1) * INT_F + f];
        float w2 = W[(4 * kg + 2) * INT_F + f];
        float w3 = W[(4 * kg + 3) * INT_F + f];
#pragma unroll
        for (int j = 0; j < 16; ++j) {
            float4 av = *(const float4*)&as[rg * 16 + j][4 * kg];  // b128 broadcast
            acc[j] += av.x * w0 + av.y * w1 + av.z * w2 + av.w * w3;
        }
    }
#pragma unroll
    for (int j = 0; j < 16; ++j) {
        size_t idx = (size_t)(base + rg * 16 + j) * INT_F + f;
        float z = acc[j];
        float nh = h[idx] + ((z >= 0.0f) ? z : NEG_SLOPE * z);
        h[idx] = nh;
        h16[idx] = __float2half(nh);
    }
}

// ---- out = h @ W_out + b_out  (8 nodes per 256-thread block) ----
__global__ void gemm_out_kernel(const float* __restrict__ h, const float* __restrict__ W,
                                const float* __restrict__ b, float* __restrict__ out) {
    __shared__ float hr[8][INT_F];
    int base = blockIdx.x * 8;
    for (int t = threadIdx.x; t < 8 * INT_F; t += 256) {
        int n = t / INT_F, k = t % INT_F;
        int gn = base + n;
        hr[n][k] = (gn < N_NODES) ? h[(size_t)gn * INT_F + k] : 0.0f;
    }
    __syncthreads();
    int nl = threadIdx.x / OUT_F;
    int f = threadIdx.x % OUT_F;
    int node = base + nl;
    if (node >= N_NODES) return;
    float acc = b[f];
#pragma unroll 8
    for (int k = 0; k < INT_F; ++k) acc += hr[nl][k] * W[k * OUT_F + f];
    out[(size_t)node * OUT_F + f] = acc;
}

extern "C" void kernel_launch(void* const* d_in, const int* in_sizes, int n_in,
                              void* d_out, int out_size, void* d_ws, size_t ws_size,
                              hipStream_t stream) {
    const float* X        = (const float*)d_in[0];
    const int2*  ei       = (const int2*)d_in[1];
    const float* ew       = (const float*)d_in[2];
    const float* W_in     = (const float*)d_in[3];
    const float* b_in     = (const float*)d_in[4];
    const float* W_layers = (const float*)d_in[5];
    const float* b_layers = (const float*)d_in[6];
    const float* W_out    = (const float*)d_in[7];
    const float* b_out    = (const float*)d_in[8];

    float* out1 = (float*)d_out;                   // (N_NODES, OUT_F)
    float* h    = out1 + (size_t)N_NODES * OUT_F;  // (N_NODES, INT_F) -- second output doubles as h

    // workspace layout (~31.5 MB)
    char* ws = (char*)d_ws;
    __half* h16   = (__half*)ws;  ws += (size_t)N_NODES * INT_F * 2;  // 12.8 MB
    __half* agg16 = (__half*)ws;  ws += (size_t)N_NODES * INT_F * 2;  // 12.8 MB
    float* csr_w   = (float*)ws;  ws += (size_t)N_EDGES * 4;          // 2.5 MB
    int*   csr_src = (int*)ws;    ws += (size_t)N_EDGES * 4;          // 2.5 MB
    int*   row_ptr = (int*)ws;    ws += (size_t)(N_NODES + 1) * 4;
    int*   cursor  = (int*)ws;    ws += (size_t)N_NODES * 4;
    int*   deg     = (int*)ws;    ws += (size_t)N_NODES * 4;
    int*   partial = (int*)ws;    ws += (size_t)SCAN_BLOCKS * 4;
    int*   bbase   = (int*)ws;    ws += (size_t)SCAN_BLOCKS * 4;

    // ---- build CSR (once per call) ----
    hipMemsetAsync(deg, 0, (size_t)N_NODES * 4, stream);
    deg_kernel<<<(N_EDGES + 255) / 256, 256, 0, stream>>>(ei, deg);
    scan1_kernel<<<SCAN_BLOCKS, 256, 0, stream>>>(deg, partial);
    scan2_kernel<<<1, 256, 0, stream>>>(partial, bbase, row_ptr);
    scan3_kernel<<<SCAN_BLOCKS, 256, 0, stream>>>(deg, bbase, row_ptr, cursor);
    build_csr_kernel<<<(N_EDGES + 255) / 256, 256, 0, stream>>>(ei, ew, cursor, csr_src, csr_w);

    // ---- input projection ----
    gemm_in_kernel<<<N_NODES / 16, 256, 0, stream>>>(X, W_in, b_in, h, h16);

    // ---- layers ----
    for (int i = 0; i < DEPTH; ++i) {
        gather_kernel<<<(N_NODES * 32 + 255) / 256, 256, 0, stream>>>(
            row_ptr, csr_src, csr_w, (const uint2*)h16, (uint2*)agg16);
        layer_gemm_kernel<<<(N_NODES + 31) / 32, 256, 0, stream>>>(
            (const uint4*)agg16, W_layers + (size_t)i * INT_F * INT_F,
            b_layers + (size_t)i * INT_F, h, h16);
    }

    // ---- output projection ----
    gemm_out_kernel<<<(N_NODES + 7) / 8, 256, 0, stream>>>(h, W_out, b_out, out1);
}